// Round 2
// 369.896 us; speedup vs baseline: 1.0063x; 1.0063x over previous
//
#include <hip/hip_runtime.h>

// ForgetMult: h_t = f_t*x_t + (1-f_t)*h_{t-1}, shapes (S=4096, B=16, H=512) fp32.
// R5 = R4 with the nontemporal-store type fixed (clang requires a native vector
// type, not HIP's float4 class). Scheme: deterministic 3-kernel two-level scan:
//   - K1/K3: explicit 8-deep register batching of the f/x loads (R3's 36-VGPR
//     build held ~2 loads in flight -> 2.6 TB/s; force ~16 outstanding).
//   - K2: batch-prefetch 16 chunk aggregates into registers per step.
//   - K3: nontemporal stores for `out` so the 128 MB output stream does not
//     evict the LLC-resident f,x (256 MB, exactly LLC-sized) being re-read.

#define SQ      4096
#define NC4     2048            // float4 columns = 16*512/4
#define NCH     8192            // scalar chains
#define TT      32              // timesteps per chunk
#define NCHUNK  (SQ / TT)       // 128
#define CB      8               // col-blocks per chunk (2048/256)
#define GRID1   (NCHUNK * CB)   // 1024 blocks for K1/K3

typedef float floatx4 __attribute__((ext_vector_type(4)));

// ---- K1: chunk aggregates (A = prod(1-f), B = local scan) ----
__global__ __launch_bounds__(256, 4)
void fm_agg(const float4* __restrict__ f4, const float4* __restrict__ x4,
            float4* __restrict__ aggA, float4* __restrict__ aggB)
{
  const int tid   = threadIdx.x;
  const int chunk = blockIdx.x >> 3;
  const int col   = ((blockIdx.x & 7) << 8) + tid;
  const size_t base = (size_t)(chunk * TT) * NC4 + col;

  float ax = 1.f, ay = 1.f, az = 1.f, aw = 1.f;
  float bx = 0.f, by = 0.f, bz = 0.f, bw = 0.f;

  for (int batch = 0; batch < TT / 8; ++batch) {
    float4 ff[8], xx[8];
#pragma unroll
    for (int i = 0; i < 8; ++i) {
      const size_t idx = base + (size_t)(batch * 8 + i) * NC4;
      ff[i] = f4[idx];
      xx[i] = x4[idx];
    }
#pragma unroll
    for (int i = 0; i < 8; ++i) {
      bx = fmaf(ff[i].x, xx[i].x - bx, bx);
      by = fmaf(ff[i].y, xx[i].y - by, by);
      bz = fmaf(ff[i].z, xx[i].z - bz, bz);
      bw = fmaf(ff[i].w, xx[i].w - bw, bw);
      ax = fmaf(-ff[i].x, ax, ax);
      ay = fmaf(-ff[i].y, ay, ay);
      az = fmaf(-ff[i].z, az, az);
      aw = fmaf(-ff[i].w, aw, aw);
    }
  }
  float4 A; A.x = ax; A.y = ay; A.z = az; A.w = aw;
  float4 B; B.x = bx; B.y = by; B.z = bz; B.w = bw;
  // Normal (cached) stores: K2/K3 read these within ~10 us.
  aggA[(size_t)chunk * NC4 + col] = A;
  aggB[(size_t)chunk * NC4 + col] = B;
}

// ---- K2: scan chunk aggregates per scalar chain ----
// Scalar view of aggA/aggB: [chunk][8192 chains]. hprev[c][chain] = h entering
// chunk c. 16-deep register prefetch decouples loads from the serial fma chain.
__global__ __launch_bounds__(256, 4)
void fm_mid(const float* __restrict__ A, const float* __restrict__ B,
            const float* __restrict__ h0, float* __restrict__ hprev)
{
  const int chain = blockIdx.x * 256 + threadIdx.x;
  float h = h0[chain];
  for (int cb = 0; cb < NCHUNK / 16; ++cb) {
    float a[16], b[16];
#pragma unroll
    for (int i = 0; i < 16; ++i) {
      const size_t idx = (size_t)(cb * 16 + i) * NCH + chain;
      a[i] = A[idx];
      b[i] = B[idx];
    }
#pragma unroll
    for (int i = 0; i < 16; ++i) {
      const size_t idx = (size_t)(cb * 16 + i) * NCH + chain;
      hprev[idx] = h;
      h = fmaf(a[i], h, b[i]);
    }
  }
}

// ---- K3: apply recurrence from hprev ----
__global__ __launch_bounds__(256, 4)
void fm_apply(const float4* __restrict__ f4, const float4* __restrict__ x4,
              const float4* __restrict__ hprev4, float4* __restrict__ out4)
{
  const int tid   = threadIdx.x;
  const int chunk = (NCHUNK - 1) - (blockIdx.x >> 3);   // descending: LLC reuse
  const int col   = ((blockIdx.x & 7) << 8) + tid;
  const size_t base = (size_t)(chunk * TT) * NC4 + col;

  floatx4* __restrict__ outv = (floatx4*)out4;

  float4 h = hprev4[(size_t)chunk * NC4 + col];
  for (int batch = 0; batch < TT / 8; ++batch) {
    float4 ff[8], xx[8];
#pragma unroll
    for (int i = 0; i < 8; ++i) {
      const size_t idx = base + (size_t)(batch * 8 + i) * NC4;
      ff[i] = f4[idx];
      xx[i] = x4[idx];
    }
#pragma unroll
    for (int i = 0; i < 8; ++i) {
      h.x = fmaf(ff[i].x, xx[i].x - h.x, h.x);
      h.y = fmaf(ff[i].y, xx[i].y - h.y, h.y);
      h.z = fmaf(ff[i].z, xx[i].z - h.z, h.z);
      h.w = fmaf(ff[i].w, xx[i].w - h.w, h.w);
      // Nontemporal: don't let the 128 MB output stream evict f,x from LLC.
      floatx4 hv; hv.x = h.x; hv.y = h.y; hv.z = h.z; hv.w = h.w;
      __builtin_nontemporal_store(hv, &outv[base + (size_t)(batch * 8 + i) * NC4]);
    }
  }
}

// Fallback (only if ws_size is too small): one float4-column per thread.
__global__ void fm_naive(const float4* __restrict__ f4, const float4* __restrict__ x4,
                         const float4* __restrict__ h04, float4* __restrict__ out4)
{
  const int col = blockIdx.x * blockDim.x + threadIdx.x;
  if (col >= NC4) return;
  float4 h = h04[col];
  for (int t = 0; t < SQ; ++t) {
    const size_t idx = (size_t)t * NC4 + col;
    const float4 ff = f4[idx], xx = x4[idx];
    h.x = fmaf(ff.x, xx.x - h.x, h.x);
    h.y = fmaf(ff.y, xx.y - h.y, h.y);
    h.z = fmaf(ff.z, xx.z - h.z, h.z);
    h.w = fmaf(ff.w, xx.w - h.w, h.w);
    out4[idx] = h;
  }
}

extern "C" void kernel_launch(void* const* d_in, const int* in_sizes, int n_in,
                              void* d_out, int out_size, void* d_ws, size_t ws_size,
                              hipStream_t stream)
{
  const float4* f4  = (const float4*)d_in[0];
  const float4* x4  = (const float4*)d_in[1];
  const float4* h04 = (const float4*)d_in[2];
  float4* out4 = (float4*)d_out;

  const size_t AGG = (size_t)NCHUNK * NC4 * 16;   // 4 MB per aggregate array
  const size_t HPV = (size_t)NCHUNK * NCH * 4;    // 4 MB hprev
  const size_t need = 2 * AGG + HPV;              // 12 MB

  if (ws_size >= need) {
    float4* aggA   = (float4*)d_ws;
    float4* aggB   = (float4*)((char*)d_ws + AGG);
    float*  hprev  = (float*)((char*)d_ws + 2 * AGG);
    fm_agg<<<GRID1, 256, 0, stream>>>(f4, x4, aggA, aggB);
    fm_mid<<<NCH / 256, 256, 0, stream>>>((const float*)aggA, (const float*)aggB,
                                          (const float*)h04, hprev);
    fm_apply<<<GRID1, 256, 0, stream>>>(f4, x4, (const float4*)hprev, out4);
  } else {
    fm_naive<<<(NC4 + 255) / 256, 256, 0, stream>>>(f4, x4, h04, out4);
  }
}

// Round 3
// 366.654 us; speedup vs baseline: 1.0152x; 1.0088x over previous
//
#include <hip/hip_runtime.h>

// ForgetMult: h_t = f_t*x_t + (1-f_t)*h_{t-1}, shapes (S=4096, B=16, H=512) fp32.
// R6: occupancy fix. R5 profile: fm_agg VGPR=36 (scheduler undid the load
// batching), OccupancyPercent=30% (grid 1024 = 4 blocks/CU = half the wave
// slots), VALUBusy=2% -> latency-bound with too few waves. Halve TT to 16 so
// grid = 2048 blocks = 8 blocks/CU = 32 waves/CU. hprev folded into aggB
// in-place so the TT=16 path needs only 16 MB workspace. TT=32 and naive
// tiers kept as fallbacks.

#define SQ      4096
#define NC4     2048            // float4 columns = 16*512/4
#define NCH     8192            // scalar chains

typedef float floatx4 __attribute__((ext_vector_type(4)));

// ---- K1: chunk aggregates (A = prod(1-f), B = local scan) ----
template<int TT_>
__global__ __launch_bounds__(256, 4)
void fm_agg(const float4* __restrict__ f4, const float4* __restrict__ x4,
            float4* __restrict__ aggA, float4* __restrict__ aggB)
{
  const int tid   = threadIdx.x;
  const int chunk = blockIdx.x >> 3;
  const int col   = ((blockIdx.x & 7) << 8) + tid;
  const size_t base = (size_t)(chunk * TT_) * NC4 + col;

  float ax = 1.f, ay = 1.f, az = 1.f, aw = 1.f;
  float bx = 0.f, by = 0.f, bz = 0.f, bw = 0.f;

  for (int batch = 0; batch < TT_ / 8; ++batch) {
    float4 ff[8], xx[8];
#pragma unroll
    for (int i = 0; i < 8; ++i) {
      const size_t idx = base + (size_t)(batch * 8 + i) * NC4;
      ff[i] = f4[idx];
      xx[i] = x4[idx];
    }
#pragma unroll
    for (int i = 0; i < 8; ++i) {
      bx = fmaf(ff[i].x, xx[i].x - bx, bx);
      by = fmaf(ff[i].y, xx[i].y - by, by);
      bz = fmaf(ff[i].z, xx[i].z - bz, bz);
      bw = fmaf(ff[i].w, xx[i].w - bw, bw);
      ax = fmaf(-ff[i].x, ax, ax);
      ay = fmaf(-ff[i].y, ay, ay);
      az = fmaf(-ff[i].z, az, az);
      aw = fmaf(-ff[i].w, aw, aw);
    }
  }
  float4 A; A.x = ax; A.y = ay; A.z = az; A.w = aw;
  float4 B; B.x = bx; B.y = by; B.z = bz; B.w = bw;
  aggA[(size_t)chunk * NC4 + col] = A;
  aggB[(size_t)chunk * NC4 + col] = B;
}

// ---- K2: scan chunk aggregates per scalar chain, hprev written IN PLACE ----
// Scalar view of aggA/aggB: [chunk][8192 chains]. For each chunk c we read
// (a,b), store the incoming h into the B slot (it becomes hprev for K3),
// then advance h = a*h + b. 16-deep register prefetch decouples the loads
// from the serial fma chain; prefetch happens before the in-place store.
template<int NCHUNK_>
__global__ __launch_bounds__(256, 4)
void fm_mid(const float* __restrict__ A, float* __restrict__ B,
            const float* __restrict__ h0)
{
  const int chain = blockIdx.x * 256 + threadIdx.x;
  float h = h0[chain];
  for (int cb = 0; cb < NCHUNK_ / 16; ++cb) {
    float a[16], b[16];
#pragma unroll
    for (int i = 0; i < 16; ++i) {
      const size_t idx = (size_t)(cb * 16 + i) * NCH + chain;
      a[i] = A[idx];
      b[i] = B[idx];
    }
#pragma unroll
    for (int i = 0; i < 16; ++i) {
      const size_t idx = (size_t)(cb * 16 + i) * NCH + chain;
      B[idx] = h;                    // hprev entering chunk cb*16+i
      h = fmaf(a[i], h, b[i]);
    }
  }
}

// ---- K3: apply recurrence from hprev (= aggB after K2) ----
template<int TT_>
__global__ __launch_bounds__(256, 4)
void fm_apply(const float4* __restrict__ f4, const float4* __restrict__ x4,
              const float4* __restrict__ hprev4, float4* __restrict__ out4)
{
  const int NCHUNK_ = SQ / TT_;
  const int tid   = threadIdx.x;
  const int chunk = (NCHUNK_ - 1) - (blockIdx.x >> 3);   // descending: LLC reuse
  const int col   = ((blockIdx.x & 7) << 8) + tid;
  const size_t base = (size_t)(chunk * TT_) * NC4 + col;

  floatx4* __restrict__ outv = (floatx4*)out4;

  float4 h = hprev4[(size_t)chunk * NC4 + col];
  for (int batch = 0; batch < TT_ / 8; ++batch) {
    float4 ff[8], xx[8];
#pragma unroll
    for (int i = 0; i < 8; ++i) {
      const size_t idx = base + (size_t)(batch * 8 + i) * NC4;
      ff[i] = f4[idx];
      xx[i] = x4[idx];
    }
#pragma unroll
    for (int i = 0; i < 8; ++i) {
      h.x = fmaf(ff[i].x, xx[i].x - h.x, h.x);
      h.y = fmaf(ff[i].y, xx[i].y - h.y, h.y);
      h.z = fmaf(ff[i].z, xx[i].z - h.z, h.z);
      h.w = fmaf(ff[i].w, xx[i].w - h.w, h.w);
      // Nontemporal: don't let the 128 MB output stream evict f,x from LLC.
      floatx4 hv; hv.x = h.x; hv.y = h.y; hv.z = h.z; hv.w = h.w;
      __builtin_nontemporal_store(hv, &outv[base + (size_t)(batch * 8 + i) * NC4]);
    }
  }
}

// Fallback (only if ws_size is too small): one float4-column per thread.
__global__ void fm_naive(const float4* __restrict__ f4, const float4* __restrict__ x4,
                         const float4* __restrict__ h04, float4* __restrict__ out4)
{
  const int col = blockIdx.x * blockDim.x + threadIdx.x;
  if (col >= NC4) return;
  float4 h = h04[col];
  for (int t = 0; t < SQ; ++t) {
    const size_t idx = (size_t)t * NC4 + col;
    const float4 ff = f4[idx], xx = x4[idx];
    h.x = fmaf(ff.x, xx.x - h.x, h.x);
    h.y = fmaf(ff.y, xx.y - h.y, h.y);
    h.z = fmaf(ff.z, xx.z - h.z, h.z);
    h.w = fmaf(ff.w, xx.w - h.w, h.w);
    out4[idx] = h;
  }
}

extern "C" void kernel_launch(void* const* d_in, const int* in_sizes, int n_in,
                              void* d_out, int out_size, void* d_ws, size_t ws_size,
                              hipStream_t stream)
{
  const float4* f4  = (const float4*)d_in[0];
  const float4* x4  = (const float4*)d_in[1];
  const float4* h04 = (const float4*)d_in[2];
  float4* out4 = (float4*)d_out;

  // Per-aggregate-array bytes: NCHUNK * NC4 * 16 = 128 MB / TT.
  const size_t AGG16 = (size_t)(SQ / 16) * NC4 * 16;   // 8 MB
  const size_t AGG32 = (size_t)(SQ / 32) * NC4 * 16;   // 4 MB

  if (ws_size >= 2 * AGG16) {                          // 16 MB: TT=16 path
    float4* aggA = (float4*)d_ws;
    float4* aggB = (float4*)((char*)d_ws + AGG16);
    fm_agg<16><<<(SQ / 16) * 8, 256, 0, stream>>>(f4, x4, aggA, aggB);
    fm_mid<SQ / 16><<<NCH / 256, 256, 0, stream>>>((const float*)aggA,
                                                   (float*)aggB, (const float*)h04);
    fm_apply<16><<<(SQ / 16) * 8, 256, 0, stream>>>(f4, x4, (const float4*)aggB, out4);
  } else if (ws_size >= 2 * AGG32) {                   // 8 MB: TT=32 path
    float4* aggA = (float4*)d_ws;
    float4* aggB = (float4*)((char*)d_ws + AGG32);
    fm_agg<32><<<(SQ / 32) * 8, 256, 0, stream>>>(f4, x4, aggA, aggB);
    fm_mid<SQ / 32><<<NCH / 256, 256, 0, stream>>>((const float*)aggA,
                                                   (float*)aggB, (const float*)h04);
    fm_apply<32><<<(SQ / 32) * 8, 256, 0, stream>>>(f4, x4, (const float4*)aggB, out4);
  } else {
    fm_naive<<<(NC4 + 255) / 256, 256, 0, stream>>>(f4, x4, h04, out4);
  }
}